// Round 1
// baseline (301.906 us; speedup 1.0000x reference)
//
#include <hip/hip_runtime.h>

// Deformable conv2d (v1 semantics, align_corners=True, zeros padding).
// Shapes (fixed per setup_inputs): x(4,64,128,128) f32, offset(4,18,128,128) f32,
// weight(64,64,9) f32 -> out(4,64,128,128) f32.
// Sampling position reduces to iy = oh + off_y, ix = ow + off_x (verified
// algebraically against the reference's normalized-coord round trip).

#define NB 4
#define CI 64
#define HH 128
#define WW 128
#define OCH 64
#define KNN 9
#define HW (HH * WW)

// weight transpose: (OC, C, KN) -> (KN, C, OC) so the per-(kn,c) 64 output-channel
// weights are 256 contiguous bytes (wave-uniform address -> s_load_dwordx16).
__global__ void wt_transpose_kernel(const float* __restrict__ w, float* __restrict__ wt) {
    int i = blockIdx.x * blockDim.x + threadIdx.x;
    if (i >= OCH * CI * KNN) return;
    int kn = i % KNN;
    int t = i / KNN;
    int c = t % CI;
    int oc = t / CI;
    wt[(kn * CI + c) * OCH + oc] = w[i];
}

template <bool USE_WT>
__global__ __launch_bounds__(256) void deform_conv_kernel(
    const float* __restrict__ x, const float* __restrict__ off,
    const float* __restrict__ wsrc, float* __restrict__ out) {
    int p = blockIdx.x * blockDim.x + threadIdx.x;  // pixel id over N*H*W
    int n = p / HW;
    int r = p % HW;
    int oh = r / WW;
    int ow = r % WW;

    float acc[OCH];
#pragma unroll
    for (int i = 0; i < OCH; i++) acc[i] = 0.f;

    const float* xn = x + n * (CI * HW);
    const float* offn = off + n * (2 * KNN * HW);

    for (int kn = 0; kn < KNN; kn++) {
        float offy = offn[(2 * kn) * HW + r];
        float offx = offn[(2 * kn + 1) * HW + r];
        float iy = (float)oh + offy;
        float ix = (float)ow + offx;

        float y0f = floorf(iy);
        float x0f = floorf(ix);
        float y1f = y0f + 1.f;
        float x1f = x0f + 1.f;
        float wy1 = iy - y0f, wy0 = 1.f - wy1;
        float wx1 = ix - x0f, wx0 = 1.f - wx1;

        // per-corner in-bounds masks (reference semantics: mask on the corner coord)
        float my0 = (y0f >= 0.f && y0f <= (float)(HH - 1)) ? 1.f : 0.f;
        float my1 = (y1f >= 0.f && y1f <= (float)(HH - 1)) ? 1.f : 0.f;
        float mx0 = (x0f >= 0.f && x0f <= (float)(WW - 1)) ? 1.f : 0.f;
        float mx1 = (x1f >= 0.f && x1f <= (float)(WW - 1)) ? 1.f : 0.f;

        float w00 = wy0 * wx0 * my0 * mx0;
        float w01 = wy0 * wx1 * my0 * mx1;
        float w10 = wy1 * wx0 * my1 * mx0;
        float w11 = wy1 * wx1 * my1 * mx1;

        int y0 = min(max((int)y0f, 0), HH - 1);
        int y1 = min(max((int)y0f + 1, 0), HH - 1);
        int x0 = min(max((int)x0f, 0), WW - 1);
        int x1 = min(max((int)x0f + 1, 0), WW - 1);

        int o00 = y0 * WW + x0;
        int o01 = y0 * WW + x1;
        int o10 = y1 * WW + x0;
        int o11 = y1 * WW + x1;

        for (int c = 0; c < CI; c++) {
            const float* xc = xn + c * HW;
            float s = xc[o00] * w00 + xc[o01] * w01 + xc[o10] * w10 + xc[o11] * w11;
#pragma unroll
            for (int oc = 0; oc < OCH; oc++) {
                float wv = USE_WT ? wsrc[(kn * CI + c) * OCH + oc]
                                  : wsrc[(oc * CI + c) * KNN + kn];
                acc[oc] += wv * s;
            }
        }
    }

    float* outp = out + n * (OCH * HW) + r;
#pragma unroll
    for (int oc = 0; oc < OCH; oc++) outp[oc * HW] = acc[oc];
}

extern "C" void kernel_launch(void* const* d_in, const int* in_sizes, int n_in,
                              void* d_out, int out_size, void* d_ws, size_t ws_size,
                              hipStream_t stream) {
    const float* x = (const float*)d_in[0];
    const float* off = (const float*)d_in[1];
    const float* w = (const float*)d_in[2];
    float* out = (float*)d_out;

    const int npix = NB * HH * WW;           // 65536
    const int welems = OCH * CI * KNN;       // 36864

    bool use_wt = ws_size >= (size_t)welems * sizeof(float);
    if (use_wt) {
        float* wt = (float*)d_ws;
        wt_transpose_kernel<<<(welems + 255) / 256, 256, 0, stream>>>(w, wt);
        deform_conv_kernel<true><<<npix / 256, 256, 0, stream>>>(x, off, wt, out);
    } else {
        deform_conv_kernel<false><<<npix / 256, 256, 0, stream>>>(x, off, w, out);
    }
}

// Round 2
// 118.926 us; speedup vs baseline: 2.5386x; 2.5386x over previous
//
#include <hip/hip_runtime.h>

// Deformable conv2d (v1, align_corners=True, zeros padding) as fused
// NHWC-bf16 deformable-im2col + MFMA GEMM.
// x(4,64,128,128) f32, offset(4,18,128,128) f32, weight(64,64,9) f32
// -> out(4,64,128,128) f32.  iy = oh + off_y, ix = ow + off_x.

#define NB 4
#define CI 64
#define HH 128
#define WW 128
#define OCH 64
#define KNN 9
#define HW (HH * WW)

typedef unsigned int u32;
typedef unsigned short u16;
typedef __attribute__((ext_vector_type(8))) short bf16x8;
typedef __attribute__((ext_vector_type(4))) float f32x4;

__device__ inline u16 f2bf(float f) {  // RNE, inputs are well-behaved (no NaN)
    u32 u = __float_as_uint(f);
    return (u16)((u + 0x7fffu + ((u >> 16) & 1u)) >> 16);
}
__device__ inline u32 pk2(float lo, float hi) {
    return (u32)f2bf(lo) | ((u32)f2bf(hi) << 16);
}
__device__ inline void up2(u32 u, float& lo, float& hi) {
    lo = __uint_as_float(u << 16);
    hi = __uint_as_float(u & 0xffff0000u);
}

// ---- prologue 1: x NCHW f32 -> NHWC bf16 (LDS tile transpose, coalesced both sides)
__global__ __launch_bounds__(256) void nhwc_kernel(const float* __restrict__ x,
                                                   u16* __restrict__ xT) {
    __shared__ float T[64 * 68];  // 64 c x 64 hw, stride 68 (16B-aligned rows, pad)
    const int tid = threadIdx.x;
    const int n = blockIdx.x >> 8;
    const int hw0 = (blockIdx.x & 255) << 6;
#pragma unroll
    for (int jj = 0; jj < 4; jj++) {
        int c = (tid >> 4) + (jj << 4);
        int hwq = (tid & 15) << 2;
        float4 v = *(const float4*)&x[(((n << 6) + c) << 14) + hw0 + hwq];
        *(float4*)&T[c * 68 + hwq] = v;
    }
    __syncthreads();
    const int hw_l = tid >> 2;
    const int cb = (tid & 3) << 4;
    u32 ou[8];
#pragma unroll
    for (int k = 0; k < 8; k++) {
        ou[k] = pk2(T[(cb + 2 * k) * 68 + hw_l], T[(cb + 2 * k + 1) * 68 + hw_l]);
    }
    u16* dst = xT + ((size_t)((n << 14) + hw0 + hw_l) << 6) + cb;
    *(uint4*)dst = make_uint4(ou[0], ou[1], ou[2], ou[3]);
    *(uint4*)(dst + 8) = make_uint4(ou[4], ou[5], ou[6], ou[7]);
}

// ---- prologue 2: weight (OC,C,KN) f32 -> A-fragment-ordered bf16
// layout: frag[kn][chunk(2)][strip(4)][lane(64)][j(8)]; lane holds
// A[m=lane&15][k=(lane>>4)*8+j], oc = strip*16+m, c = chunk*32+k.
__global__ void wfrag_kernel(const float* __restrict__ w, u16* __restrict__ wf) {
    int i = blockIdx.x * 256 + threadIdx.x;
    if (i >= KNN * 2 * 4 * 64 * 8) return;
    int j = i & 7, l = (i >> 3) & 63, strip = (i >> 9) & 3, chunk = (i >> 11) & 1,
        kn = i >> 12;
    int oc = strip * 16 + (l & 15);
    int c = chunk * 32 + ((l >> 4) & 3) * 8 + j;
    wf[i] = f2bf(w[(oc * CI + c) * KNN + kn]);
}

// ---- main: per block, 64-pixel half-row x 64 oc; loop kn: sample S[64pix][64c]
// bf16 into LDS, then 16x16x32 bf16 MFMA accumulate W*S.
__global__ __launch_bounds__(256) void dcn_main_kernel(const u16* __restrict__ xT,
                                                       const float* __restrict__ off,
                                                       const u16* __restrict__ wf,
                                                       float* __restrict__ out) {
    __shared__ u16 S[64 * 72];  // row=pix, 64 c + 8 pad (144B rows, 16B-aligned)
    const int tid = threadIdx.x;
    const int n = blockIdx.x >> 8;
    const int r0 = (blockIdx.x & 255) << 6;
    const int pix = tid & 63, cq = tid >> 6;
    const int r = r0 + pix;
    const int oh = r >> 7, ow = r & 127;
    const u16* xTn = xT + ((size_t)n << 20);  // n*HW*64
    const float* offn = off + n * (2 * KNN * HW);
    const int wv = tid >> 6, l = tid & 63;
    const int brow = l & 15;
    const int bco = (l >> 4) << 3;  // 8*(l>>4) ushorts into the c-dim
    f32x4 acc[4] = {{0, 0, 0, 0}, {0, 0, 0, 0}, {0, 0, 0, 0}, {0, 0, 0, 0}};

    for (int kn = 0; kn < KNN; kn++) {
        // ---- sampling (global loads kept outside the barrier window)
        float offy = offn[(2 * kn) * HW + r];
        float offx = offn[(2 * kn + 1) * HW + r];
        float iy = (float)oh + offy, ix = (float)ow + offx;
        float y0f = floorf(iy), x0f = floorf(ix);
        float wy1 = iy - y0f, wy0 = 1.f - wy1;
        float wx1 = ix - x0f, wx0 = 1.f - wx1;
        float my0 = (y0f >= 0.f && y0f <= 127.f) ? 1.f : 0.f;
        float my1 = (y0f >= -1.f && y0f <= 126.f) ? 1.f : 0.f;
        float mx0 = (x0f >= 0.f && x0f <= 127.f) ? 1.f : 0.f;
        float mx1 = (x0f >= -1.f && x0f <= 126.f) ? 1.f : 0.f;
        float w00 = wy0 * wx0 * my0 * mx0, w01 = wy0 * wx1 * my0 * mx1;
        float w10 = wy1 * wx0 * my1 * mx0, w11 = wy1 * wx1 * my1 * mx1;
        int y0 = min(max((int)y0f, 0), 127), y1 = min(max((int)y0f + 1, 0), 127);
        int x0 = min(max((int)x0f, 0), 127), x1 = min(max((int)x0f + 1, 0), 127);
        const int cqo = cq << 4;
        const uint4* p00 = (const uint4*)(xTn + (((y0 << 7) + x0) << 6) + cqo);
        const uint4* p01 = (const uint4*)(xTn + (((y0 << 7) + x1) << 6) + cqo);
        const uint4* p10 = (const uint4*)(xTn + (((y1 << 7) + x0) << 6) + cqo);
        const uint4* p11 = (const uint4*)(xTn + (((y1 << 7) + x1) << 6) + cqo);
        u32 c00[8], c01[8], c10[8], c11[8];
        *(uint4*)&c00[0] = p00[0]; *(uint4*)&c00[4] = p00[1];
        *(uint4*)&c01[0] = p01[0]; *(uint4*)&c01[4] = p01[1];
        *(uint4*)&c10[0] = p10[0]; *(uint4*)&c10[4] = p10[1];
        *(uint4*)&c11[0] = p11[0]; *(uint4*)&c11[4] = p11[1];
        u32 ou[8];
#pragma unroll
        for (int k = 0; k < 8; k++) {
            float a0, b0, a1, b1, a2, b2, a3, b3;
            up2(c00[k], a0, b0); up2(c01[k], a1, b1);
            up2(c10[k], a2, b2); up2(c11[k], a3, b3);
            float slo = a0 * w00 + a1 * w01 + a2 * w10 + a3 * w11;
            float shi = b0 * w00 + b1 * w01 + b2 * w10 + b3 * w11;
            ou[k] = pk2(slo, shi);
        }
        __syncthreads();  // previous iteration's MFMA reads of S are done
        uint4* sp = (uint4*)&S[pix * 72 + cqo];
        sp[0] = make_uint4(ou[0], ou[1], ou[2], ou[3]);
        sp[1] = make_uint4(ou[4], ou[5], ou[6], ou[7]);
        __syncthreads();  // S tile ready
        // ---- MFMA phase: wave wv owns oc strip [16wv,16wv+16), 4 pixel tiles
        bf16x8 A0 = ((const bf16x8*)wf)[((kn * 2 + 0) * 4 + wv) * 64 + l];
        bf16x8 A1 = ((const bf16x8*)wf)[((kn * 2 + 1) * 4 + wv) * 64 + l];
#pragma unroll
        for (int t = 0; t < 4; t++) {
            bf16x8 B0 = *(const bf16x8*)&S[((t << 4) + brow) * 72 + bco];
            bf16x8 B1 = *(const bf16x8*)&S[((t << 4) + brow) * 72 + 32 + bco];
            acc[t] = __builtin_amdgcn_mfma_f32_16x16x32_bf16(A0, B0, acc[t], 0, 0, 0);
            acc[t] = __builtin_amdgcn_mfma_f32_16x16x32_bf16(A1, B1, acc[t], 0, 0, 0);
        }
    }
    // ---- epilogue: C/D layout col(pix)=lane&15, row(oc)=(lane>>4)*4+reg
    const int colp = l & 15, rowq = l >> 4;
    float* outn = out + (size_t)(n * OCH + (wv << 4) + (rowq << 2)) * HW;
#pragma unroll
    for (int t = 0; t < 4; t++) {
        int pixg = r0 + (t << 4) + colp;
#pragma unroll
        for (int rg = 0; rg < 4; rg++) {
            outn[rg * HW + pixg] = acc[t][rg];
        }
    }
}

// ---- fallback (ws too small): round-1 style direct kernel
__global__ __launch_bounds__(256) void dcn_fallback_kernel(
    const float* __restrict__ x, const float* __restrict__ off,
    const float* __restrict__ w, float* __restrict__ out) {
    int p = blockIdx.x * blockDim.x + threadIdx.x;
    int n = p / HW, r = p % HW, oh = r / WW, ow = r % WW;
    float acc[OCH];
#pragma unroll
    for (int i = 0; i < OCH; i++) acc[i] = 0.f;
    const float* xn = x + n * (CI * HW);
    const float* offn = off + n * (2 * KNN * HW);
    for (int kn = 0; kn < KNN; kn++) {
        float iy = (float)oh + offn[(2 * kn) * HW + r];
        float ix = (float)ow + offn[(2 * kn + 1) * HW + r];
        float y0f = floorf(iy), x0f = floorf(ix);
        float wy1 = iy - y0f, wy0 = 1.f - wy1, wx1 = ix - x0f, wx0 = 1.f - wx1;
        float my0 = (y0f >= 0.f && y0f <= 127.f) ? 1.f : 0.f;
        float my1 = (y0f >= -1.f && y0f <= 126.f) ? 1.f : 0.f;
        float mx0 = (x0f >= 0.f && x0f <= 127.f) ? 1.f : 0.f;
        float mx1 = (x0f >= -1.f && x0f <= 126.f) ? 1.f : 0.f;
        float w00 = wy0 * wx0 * my0 * mx0, w01 = wy0 * wx1 * my0 * mx1;
        float w10 = wy1 * wx0 * my1 * mx0, w11 = wy1 * wx1 * my1 * mx1;
        int y0 = min(max((int)y0f, 0), 127), y1 = min(max((int)y0f + 1, 0), 127);
        int x0 = min(max((int)x0f, 0), 127), x1 = min(max((int)x0f + 1, 0), 127);
        int o00 = y0 * WW + x0, o01 = y0 * WW + x1, o10 = y1 * WW + x0, o11 = y1 * WW + x1;
        for (int c = 0; c < CI; c++) {
            const float* xc = xn + c * HW;
            float s = xc[o00] * w00 + xc[o01] * w01 + xc[o10] * w10 + xc[o11] * w11;
#pragma unroll
            for (int oc = 0; oc < OCH; oc++) acc[oc] += w[(oc * CI + c) * KNN + kn] * s;
        }
    }
    float* outp = out + n * (OCH * HW) + r;
#pragma unroll
    for (int oc = 0; oc < OCH; oc++) outp[oc * HW] = acc[oc];
}

extern "C" void kernel_launch(void* const* d_in, const int* in_sizes, int n_in,
                              void* d_out, int out_size, void* d_ws, size_t ws_size,
                              hipStream_t stream) {
    const float* x = (const float*)d_in[0];
    const float* off = (const float*)d_in[1];
    const float* w = (const float*)d_in[2];
    float* out = (float*)d_out;

    const size_t xT_elems = (size_t)NB * HW * CI;              // 4,194,304 u16
    const size_t wf_elems = (size_t)KNN * 2 * 4 * 64 * 8;      // 36,864 u16
    const size_t need = (xT_elems + wf_elems) * sizeof(u16);   // 8,462,336 B

    if (ws_size >= need) {
        u16* xT = (u16*)d_ws;
        u16* wfr = xT + xT_elems;
        nhwc_kernel<<<NB * 256, 256, 0, stream>>>(x, xT);
        wfrag_kernel<<<(int)((wf_elems + 255) / 256), 256, 0, stream>>>(w, wfr);
        dcn_main_kernel<<<NB * 256, 256, 0, stream>>>(xT, off, wfr, out);
    } else {
        dcn_fallback_kernel<<<(NB * HW) / 256, 256, 0, stream>>>(x, off, w, out);
    }
}

// Round 3
// 116.017 us; speedup vs baseline: 2.6023x; 1.0251x over previous
//
#include <hip/hip_runtime.h>

// Deformable conv2d (v1, align_corners=True, zeros padding), fused
// NHWC-bf16 direct-gather + MFMA. No LDS, no barriers in the main kernel:
// the 16x16x32 bf16 B-fragment (lane l = B[k=(l>>4)*8+j][n=l&15]) is built
// per-lane straight from 4 bilinear-corner uint4 gathers of NHWC x.
// x(4,64,128,128) f32, offset(4,18,128,128) f32, weight(64,64,9) f32
// -> out(4,64,128,128) f32.  iy = oh + off_y, ix = ow + off_x.

#define NB 4
#define CI 64
#define HH 128
#define WW 128
#define OCH 64
#define KNN 9
#define HW (HH * WW)

typedef unsigned int u32;
typedef unsigned short u16;
typedef __attribute__((ext_vector_type(8))) short bf16x8;
typedef __attribute__((ext_vector_type(4))) float f32x4;

__device__ inline u16 f2bf(float f) {  // RNE, inputs well-behaved (no NaN)
    u32 u = __float_as_uint(f);
    return (u16)((u + 0x7fffu + ((u >> 16) & 1u)) >> 16);
}
__device__ inline u32 pk2(float lo, float hi) {
    return (u32)f2bf(lo) | ((u32)f2bf(hi) << 16);
}
__device__ inline void up2(u32 u, float& lo, float& hi) {
    lo = __uint_as_float(u << 16);
    hi = __uint_as_float(u & 0xffff0000u);
}

// ---- prologue (one launch): x NCHW f32 -> NHWC bf16 tile transpose, plus
// weight (OC,C,KN) f32 -> A-fragment-ordered bf16 in the tail blocks.
// wf layout: frag[kn][chunk(2)][strip(4)][lane(64)][j(8)], lane holds
// A[m=lane&15][k=(lane>>4)*8+j], oc = strip*16+m, c = chunk*32+k.
__global__ __launch_bounds__(256) void prep_kernel(const float* __restrict__ x,
                                                   const float* __restrict__ w,
                                                   u16* __restrict__ xT,
                                                   u16* __restrict__ wf) {
    __shared__ float T[64 * 68];
    const int tid = threadIdx.x;
    if (blockIdx.x < NB * 256) {
        const int n = blockIdx.x >> 8;
        const int hw0 = (blockIdx.x & 255) << 6;
#pragma unroll
        for (int jj = 0; jj < 4; jj++) {
            int c = (tid >> 4) + (jj << 4);
            int hwq = (tid & 15) << 2;
            float4 v = *(const float4*)&x[(((n << 6) + c) << 14) + hw0 + hwq];
            *(float4*)&T[c * 68 + hwq] = v;
        }
        __syncthreads();
        const int hw_l = tid >> 2;
        const int cb = (tid & 3) << 4;
        u32 ou[8];
#pragma unroll
        for (int k = 0; k < 8; k++) {
            ou[k] = pk2(T[(cb + 2 * k) * 68 + hw_l], T[(cb + 2 * k + 1) * 68 + hw_l]);
        }
        u16* dst = xT + ((size_t)((n << 14) + hw0 + hw_l) << 6) + cb;
        *(uint4*)dst = make_uint4(ou[0], ou[1], ou[2], ou[3]);
        *(uint4*)(dst + 8) = make_uint4(ou[4], ou[5], ou[6], ou[7]);
    } else {
        int i = (blockIdx.x - NB * 256) * 256 + tid;
        if (i < KNN * 2 * 4 * 64 * 8) {
            int j = i & 7, l = (i >> 3) & 63, strip = (i >> 9) & 3,
                chunk = (i >> 11) & 1, kn = i >> 12;
            int oc = strip * 16 + (l & 15);
            int c = chunk * 32 + ((l >> 4) & 3) * 8 + j;
            wf[i] = f2bf(w[(oc * CI + c) * KNN + kn]);
        }
    }
}

// ---- main: one wave per 16 pixels x 64 oc. Per kn, per 32-channel chunk:
// 4 corner uint4 gathers -> bilinear in fp32 -> pack bf16 B-fragment ->
// 4 MFMAs (oc strips) reusing it. Barrier-free.
__global__ __launch_bounds__(256, 4) void dcn_main_kernel(const u16* __restrict__ xT,
                                                          const float* __restrict__ off,
                                                          const u16* __restrict__ wf,
                                                          float* __restrict__ out) {
    const int tid = threadIdx.x;
    const int l = tid & 63;
    const int wv = tid >> 6;
    const int gw = (blockIdx.x << 2) + wv;  // 0..4095
    const int p0 = gw << 4;                 // first pixel over N*HW
    const int n = p0 >> 14;
    const int rr0 = p0 & 16383;
    const int col = l & 15;
    const int rr = rr0 + col;               // this lane's pixel within batch
    const int oh = rr >> 7, ow = rr & 127;
    const int cbase = (l >> 4) << 3;        // 0,8,16,24
    const u16* xTn = xT + ((size_t)n << 20);
    const float* offn = off + n * (2 * KNN * HW);
    const bf16x8* wfv = (const bf16x8*)wf;

    f32x4 acc[4] = {{0, 0, 0, 0}, {0, 0, 0, 0}, {0, 0, 0, 0}, {0, 0, 0, 0}};

    for (int kn = 0; kn < KNN; kn++) {
        float offy = offn[(2 * kn) * HW + rr];
        float offx = offn[(2 * kn + 1) * HW + rr];
        float iy = (float)oh + offy, ix = (float)ow + offx;
        float y0f = floorf(iy), x0f = floorf(ix);
        float wy1 = iy - y0f, wy0 = 1.f - wy1;
        float wx1 = ix - x0f, wx0 = 1.f - wx1;
        float my0 = (y0f >= 0.f && y0f <= 127.f) ? 1.f : 0.f;
        float my1 = (y0f >= -1.f && y0f <= 126.f) ? 1.f : 0.f;
        float mx0 = (x0f >= 0.f && x0f <= 127.f) ? 1.f : 0.f;
        float mx1 = (x0f >= -1.f && x0f <= 126.f) ? 1.f : 0.f;
        float w00 = wy0 * wx0 * my0 * mx0, w01 = wy0 * wx1 * my0 * mx1;
        float w10 = wy1 * wx0 * my1 * mx0, w11 = wy1 * wx1 * my1 * mx1;
        int y0 = min(max((int)y0f, 0), 127), y1 = min(max((int)y0f + 1, 0), 127);
        int x0 = min(max((int)x0f, 0), 127), x1 = min(max((int)x0f + 1, 0), 127);
        const u16* b00 = xTn + (((y0 << 7) + x0) << 6);
        const u16* b01 = xTn + (((y0 << 7) + x1) << 6);
        const u16* b10 = xTn + (((y1 << 7) + x0) << 6);
        const u16* b11 = xTn + (((y1 << 7) + x1) << 6);
#pragma unroll
        for (int ch = 0; ch < 2; ch++) {
            const int c = (ch << 5) + cbase;
            uint4 q00 = *(const uint4*)(b00 + c);
            uint4 q01 = *(const uint4*)(b01 + c);
            uint4 q10 = *(const uint4*)(b10 + c);
            uint4 q11 = *(const uint4*)(b11 + c);
            const u32* a00 = (const u32*)&q00;
            const u32* a01 = (const u32*)&q01;
            const u32* a10 = (const u32*)&q10;
            const u32* a11 = (const u32*)&q11;
            union { u32 u[4]; bf16x8 v; } B;
#pragma unroll
            for (int k = 0; k < 4; k++) {
                float p0l, p0h, p1l, p1h, p2l, p2h, p3l, p3h;
                up2(a00[k], p0l, p0h);
                up2(a01[k], p1l, p1h);
                up2(a10[k], p2l, p2h);
                up2(a11[k], p3l, p3h);
                float slo = p0l * w00 + p1l * w01 + p2l * w10 + p3l * w11;
                float shi = p0h * w00 + p1h * w01 + p2h * w10 + p3h * w11;
                B.u[k] = pk2(slo, shi);
            }
#pragma unroll
            for (int s = 0; s < 4; s++) {
                bf16x8 A = wfv[(((kn << 1) + ch) << 2 | s) * 64 + l];
                acc[s] = __builtin_amdgcn_mfma_f32_16x16x32_bf16(A, B.v, acc[s], 0, 0, 0);
            }
        }
    }
    // epilogue: D layout col(pixel)=l&15, row(oc-in-strip)=(l>>4)*4+reg
    const int rq = l >> 4;
    float* op = out + ((size_t)(n * OCH) << 14);
#pragma unroll
    for (int s = 0; s < 4; s++) {
        const int ocb = (s << 4) + (rq << 2);
#pragma unroll
        for (int g = 0; g < 4; g++) {
            op[((ocb + g) << 14) + rr] = acc[s][g];
        }
    }
}

// ---- fallback (ws too small): round-1 style direct kernel
__global__ __launch_bounds__(256) void dcn_fallback_kernel(
    const float* __restrict__ x, const float* __restrict__ off,
    const float* __restrict__ w, float* __restrict__ out) {
    int p = blockIdx.x * blockDim.x + threadIdx.x;
    int n = p / HW, r = p % HW, oh = r / WW, ow = r % WW;
    float acc[OCH];
#pragma unroll
    for (int i = 0; i < OCH; i++) acc[i] = 0.f;
    const float* xn = x + n * (CI * HW);
    const float* offn = off + n * (2 * KNN * HW);
    for (int kn = 0; kn < KNN; kn++) {
        float iy = (float)oh + offn[(2 * kn) * HW + r];
        float ix = (float)ow + offn[(2 * kn + 1) * HW + r];
        float y0f = floorf(iy), x0f = floorf(ix);
        float wy1 = iy - y0f, wy0 = 1.f - wy1, wx1 = ix - x0f, wx0 = 1.f - wx1;
        float my0 = (y0f >= 0.f && y0f <= 127.f) ? 1.f : 0.f;
        float my1 = (y0f >= -1.f && y0f <= 126.f) ? 1.f : 0.f;
        float mx0 = (x0f >= 0.f && x0f <= 127.f) ? 1.f : 0.f;
        float mx1 = (x0f >= -1.f && x0f <= 126.f) ? 1.f : 0.f;
        float w00 = wy0 * wx0 * my0 * mx0, w01 = wy0 * wx1 * my0 * mx1;
        float w10 = wy1 * wx0 * my1 * mx0, w11 = wy1 * wx1 * my1 * mx1;
        int y0 = min(max((int)y0f, 0), 127), y1 = min(max((int)y0f + 1, 0), 127);
        int x0 = min(max((int)x0f, 0), 127), x1 = min(max((int)x0f + 1, 0), 127);
        int o00 = y0 * WW + x0, o01 = y0 * WW + x1, o10 = y1 * WW + x0, o11 = y1 * WW + x1;
        for (int c = 0; c < CI; c++) {
            const float* xc = xn + c * HW;
            float s = xc[o00] * w00 + xc[o01] * w01 + xc[o10] * w10 + xc[o11] * w11;
#pragma unroll
            for (int oc = 0; oc < OCH; oc++) acc[oc] += w[(oc * CI + c) * KNN + kn] * s;
        }
    }
    float* outp = out + n * (OCH * HW) + r;
#pragma unroll
    for (int oc = 0; oc < OCH; oc++) outp[oc * HW] = acc[oc];
}

extern "C" void kernel_launch(void* const* d_in, const int* in_sizes, int n_in,
                              void* d_out, int out_size, void* d_ws, size_t ws_size,
                              hipStream_t stream) {
    const float* x = (const float*)d_in[0];
    const float* off = (const float*)d_in[1];
    const float* w = (const float*)d_in[2];
    float* out = (float*)d_out;

    const size_t xT_elems = (size_t)NB * HW * CI;             // 4,194,304 u16
    const size_t wf_elems = (size_t)KNN * 2 * 4 * 64 * 8;     // 36,864 u16
    const size_t need = (xT_elems + wf_elems) * sizeof(u16);  // ~8.46 MB

    if (ws_size >= need) {
        u16* xT = (u16*)d_ws;
        u16* wfr = xT + xT_elems;
        const int wf_blocks = (int)((wf_elems + 255) / 256);  // 144
        prep_kernel<<<NB * 256 + wf_blocks, 256, 0, stream>>>(x, w, xT, wfr);
        dcn_main_kernel<<<1024, 256, 0, stream>>>(xT, off, wfr, out);
    } else {
        dcn_fallback_kernel<<<(NB * HW) / 256, 256, 0, stream>>>(x, off, w, out);
    }
}

// Round 4
// 110.801 us; speedup vs baseline: 2.7248x; 1.0471x over previous
//
#include <hip/hip_runtime.h>
#include <hip/hip_bf16.h>

// Deformable conv2d (v1, align_corners=True, zeros padding), fused
// NHWC-bf16 direct-gather + MFMA, software-pipelined:
//  - all 18 offsets preloaded to regs
//  - kn+1 corner gathers issued right after the barrier (full-iteration flight)
//  - weight A-fragments staged global->LDS via global_load_lds, double-buffered
// x(4,64,128,128) f32, offset(4,18,128,128) f32, weight(64,64,9) f32
// -> out(4,64,128,128) f32.  iy = oh + off_y, ix = ow + off_x.

#define NB 4
#define CI 64
#define HH 128
#define WW 128
#define OCH 64
#define KNN 9
#define HW (HH * WW)

typedef unsigned int u32;
typedef unsigned short u16;
typedef __attribute__((ext_vector_type(8))) short bf16x8;
typedef __attribute__((ext_vector_type(4))) float f32x4;

typedef const __attribute__((address_space(1))) u32* gas_ptr;
typedef __attribute__((address_space(3))) u32* las_ptr;

__device__ inline u16 f2bf(float f) {  // RNE
    u32 u = __float_as_uint(f);
    return (u16)((u + 0x7fffu + ((u >> 16) & 1u)) >> 16);
}
__device__ inline u32 pk2(float lo, float hi) {
    return (u32)f2bf(lo) | ((u32)f2bf(hi) << 16);
}
__device__ inline void up2(u32 u, float& lo, float& hi) {
    lo = __uint_as_float(u << 16);
    hi = __uint_as_float(u & 0xffff0000u);
}
__device__ inline u32 pkrn(float lo, float hi) {
    __hip_bfloat162 h = __float22bfloat162_rn(float2{lo, hi});
    union { __hip_bfloat162 b; u32 u; } c;
    c.b = h;
    return c.u;
}
__device__ inline void gload_lds16(const u16* g, u16* s) {
    __builtin_amdgcn_global_load_lds((gas_ptr)g, (las_ptr)s, 16, 0, 0);
}

// ---- prologue: x NCHW f32 -> NHWC bf16, + weight -> A-fragment order bf16.
// wf layout: frag[kn][chunk(2)][strip(4)][lane(64)][j(8)]; lane holds
// A[m=lane&15][k=(lane>>4)*8+j], oc = strip*16+m, c = chunk*32+k.
__global__ __launch_bounds__(256) void prep_kernel(const float* __restrict__ x,
                                                   const float* __restrict__ w,
                                                   u16* __restrict__ xT,
                                                   u16* __restrict__ wf) {
    __shared__ float T[64 * 68];
    const int tid = threadIdx.x;
    if (blockIdx.x < NB * 256) {
        const int n = blockIdx.x >> 8;
        const int hw0 = (blockIdx.x & 255) << 6;
#pragma unroll
        for (int jj = 0; jj < 4; jj++) {
            int c = (tid >> 4) + (jj << 4);
            int hwq = (tid & 15) << 2;
            float4 v = *(const float4*)&x[(((n << 6) + c) << 14) + hw0 + hwq];
            *(float4*)&T[c * 68 + hwq] = v;
        }
        __syncthreads();
        const int hw_l = tid >> 2;
        const int cb = (tid & 3) << 4;
        u32 ou[8];
#pragma unroll
        for (int k = 0; k < 8; k++) {
            ou[k] = pk2(T[(cb + 2 * k) * 68 + hw_l], T[(cb + 2 * k + 1) * 68 + hw_l]);
        }
        u16* dst = xT + ((size_t)((n << 14) + hw0 + hw_l) << 6) + cb;
        *(uint4*)dst = make_uint4(ou[0], ou[1], ou[2], ou[3]);
        *(uint4*)(dst + 8) = make_uint4(ou[4], ou[5], ou[6], ou[7]);
    } else {
        int i = (blockIdx.x - NB * 256) * 256 + tid;
        if (i < KNN * 2 * 4 * 64 * 8) {
            int j = i & 7, l = (i >> 3) & 63, strip = (i >> 9) & 3,
                chunk = (i >> 11) & 1, kn = i >> 12;
            int oc = strip * 16 + (l & 15);
            int c = chunk * 32 + ((l >> 4) & 3) * 8 + j;
            wf[i] = f2bf(w[(oc * CI + c) * KNN + kn]);
        }
    }
}

// ---- main kernel
__global__ __launch_bounds__(256, 3) void dcn_main_kernel(const u16* __restrict__ xT,
                                                          const float* __restrict__ off,
                                                          const u16* __restrict__ wf,
                                                          float* __restrict__ out) {
    __shared__ __align__(16) u16 Abuf[2][4096];  // 8KB per kn slot, double-buffered
    const int tid = threadIdx.x;
    const int l = tid & 63;
    const int wv = tid >> 6;
    const int gw = (blockIdx.x << 2) + wv;  // 0..4095
    const int p0 = gw << 4;
    const int n = p0 >> 14;
    const int rr0 = p0 & 16383;
    const int col = l & 15;
    const int rr = rr0 + col;
    const int oh = rr >> 7, ow = rr & 127;
    const int cbase = (l >> 4) << 3;  // 0,8,16,24
    const u16* xTn = xT + ((size_t)n << 20);
    const float* offn = off + n * (2 * KNN * HW);

    // preload all offsets (18 independent loads, off the critical path)
    float offy[KNN], offx[KNN];
#pragma unroll
    for (int kn = 0; kn < KNN; kn++) {
        offy[kn] = offn[(2 * kn) * HW + rr];
        offx[kn] = offn[(2 * kn + 1) * HW + rr];
    }

    f32x4 acc[4] = {{0, 0, 0, 0}, {0, 0, 0, 0}, {0, 0, 0, 0}, {0, 0, 0, 0}};

    float W[2][4];   // bilinear weights per parity
    int O[2][4];     // corner base offsets (u16 elements) per parity
    uint4 G0[2][4];  // chunk0 corner gathers per parity
    uint4 G1[2][4];  // chunk1

    auto calc = [&](int kn) {
        const int p = kn & 1;
        float iy = (float)oh + offy[kn], ix = (float)ow + offx[kn];
        float y0f = floorf(iy), x0f = floorf(ix);
        float wy1 = iy - y0f, wy0 = 1.f - wy1;
        float wx1 = ix - x0f, wx0 = 1.f - wx1;
        float my0 = (y0f >= 0.f && y0f <= 127.f) ? 1.f : 0.f;
        float my1 = (y0f >= -1.f && y0f <= 126.f) ? 1.f : 0.f;
        float mx0 = (x0f >= 0.f && x0f <= 127.f) ? 1.f : 0.f;
        float mx1 = (x0f >= -1.f && x0f <= 126.f) ? 1.f : 0.f;
        W[p][0] = wy0 * wx0 * my0 * mx0;
        W[p][1] = wy0 * wx1 * my0 * mx1;
        W[p][2] = wy1 * wx0 * my1 * mx0;
        W[p][3] = wy1 * wx1 * my1 * mx1;
        int y0 = min(max((int)y0f, 0), 127), y1 = min(max((int)y0f + 1, 0), 127);
        int x0 = min(max((int)x0f, 0), 127), x1 = min(max((int)x0f + 1, 0), 127);
        O[p][0] = ((y0 << 7) + x0) << 6;
        O[p][1] = ((y0 << 7) + x1) << 6;
        O[p][2] = ((y1 << 7) + x0) << 6;
        O[p][3] = ((y1 << 7) + x1) << 6;
    };
    auto gather = [&](int kn, int ch, uint4* G) {
        const int p = kn & 1;
        const int c = (ch << 5) + cbase;
#pragma unroll
        for (int k = 0; k < 4; k++) G[k] = *(const uint4*)(xTn + O[p][k] + c);
    };
    auto stageA = [&](int kn) {
        const int b = kn & 1;
        const u16* g = wf + kn * 4096 + wv * 1024 + l * 8;
        u16* s = &Abuf[b][wv * 1024 + l * 8];
        gload_lds16(g, s);
        gload_lds16(g + 512, s + 512);
    };
    auto interp = [&](int kn, const uint4* G, bf16x8& Bv) {
        const int p = kn & 1;
        const u32* a0 = (const u32*)&G[0];
        const u32* a1 = (const u32*)&G[1];
        const u32* a2 = (const u32*)&G[2];
        const u32* a3 = (const u32*)&G[3];
        union { u32 u[4]; bf16x8 v; } B;
#pragma unroll
        for (int k = 0; k < 4; k++) {
            float p0l, p0h, p1l, p1h, p2l, p2h, p3l, p3h;
            up2(a0[k], p0l, p0h);
            up2(a1[k], p1l, p1h);
            up2(a2[k], p2l, p2h);
            up2(a3[k], p3l, p3h);
            float slo = p0l * W[p][0] + p1l * W[p][1] + p2l * W[p][2] + p3l * W[p][3];
            float shi = p0h * W[p][0] + p1h * W[p][1] + p2h * W[p][2] + p3h * W[p][3];
            B.u[k] = pkrn(slo, shi);
        }
        Bv = B.v;
    };
    auto mfma_ch = [&](int kn, int ch, bf16x8 Bv) {
        const int b = kn & 1;
#pragma unroll
        for (int s4 = 0; s4 < 4; s4++) {
            bf16x8 A = *(const bf16x8*)&Abuf[b][(((ch << 2) + s4) * 64 + l) * 8];
            acc[s4] = __builtin_amdgcn_mfma_f32_16x16x32_bf16(A, Bv, acc[s4], 0, 0, 0);
        }
    };

    // prologue: kn=0 in flight
    calc(0);
    stageA(0);
    gather(0, 0, G0[0]);
    gather(0, 1, G1[0]);
    __syncthreads();  // drains stage(0)+gathers(0)

#pragma unroll
    for (int kn = 0; kn < KNN; kn++) {
        // issue kn+1 loads FIRST (max flight time until end-of-iter barrier)
        if (kn + 1 < KNN) {
            calc(kn + 1);
            stageA(kn + 1);
            gather(kn + 1, 0, G0[(kn + 1) & 1]);
        }
        bf16x8 B0;
        interp(kn, G0[kn & 1], B0);  // regs drained by previous barrier: no wait
        if (kn + 1 < KNN) gather(kn + 1, 1, G1[(kn + 1) & 1]);
        mfma_ch(kn, 0, B0);
        bf16x8 B1;
        interp(kn, G1[kn & 1], B1);
        mfma_ch(kn, 1, B1);
        __syncthreads();  // A-buf swap + drains kn+1 loads (covered by ~450cyc span)
    }

    // epilogue: D layout col(pixel)=l&15, row(oc-in-strip)=(l>>4)*4+reg
    const int rq = l >> 4;
    float* op = out + ((size_t)(n * OCH) << 14);
#pragma unroll
    for (int s = 0; s < 4; s++) {
        const int ocb = (s << 4) + (rq << 2);
#pragma unroll
        for (int g = 0; g < 4; g++) {
            op[((ocb + g) << 14) + rr] = acc[s][g];
        }
    }
}

// ---- fallback (ws too small): round-1 style direct kernel
__global__ __launch_bounds__(256) void dcn_fallback_kernel(
    const float* __restrict__ x, const float* __restrict__ off,
    const float* __restrict__ w, float* __restrict__ out) {
    int p = blockIdx.x * blockDim.x + threadIdx.x;
    int n = p / HW, r = p % HW, oh = r / WW, ow = r % WW;
    float acc[OCH];
#pragma unroll
    for (int i = 0; i < OCH; i++) acc[i] = 0.f;
    const float* xn = x + n * (CI * HW);
    const float* offn = off + n * (2 * KNN * HW);
    for (int kn = 0; kn < KNN; kn++) {
        float iy = (float)oh + offn[(2 * kn) * HW + r];
        float ix = (float)ow + offn[(2 * kn + 1) * HW + r];
        float y0f = floorf(iy), x0f = floorf(ix);
        float wy1 = iy - y0f, wy0 = 1.f - wy1, wx1 = ix - x0f, wx0 = 1.f - wx1;
        float my0 = (y0f >= 0.f && y0f <= 127.f) ? 1.f : 0.f;
        float my1 = (y0f >= -1.f && y0f <= 126.f) ? 1.f : 0.f;
        float mx0 = (x0f >= 0.f && x0f <= 127.f) ? 1.f : 0.f;
        float mx1 = (x0f >= -1.f && x0f <= 126.f) ? 1.f : 0.f;
        float w00 = wy0 * wx0 * my0 * mx0, w01 = wy0 * wx1 * my0 * mx1;
        float w10 = wy1 * wx0 * my1 * mx0, w11 = wy1 * wx1 * my1 * mx1;
        int y0 = min(max((int)y0f, 0), 127), y1 = min(max((int)y0f + 1, 0), 127);
        int x0 = min(max((int)x0f, 0), 127), x1 = min(max((int)x0f + 1, 0), 127);
        int o00 = y0 * WW + x0, o01 = y0 * WW + x1, o10 = y1 * WW + x0, o11 = y1 * WW + x1;
        for (int c = 0; c < CI; c++) {
            const float* xc = xn + c * HW;
            float s = xc[o00] * w00 + xc[o01] * w01 + xc[o10] * w10 + xc[o11] * w11;
#pragma unroll
            for (int oc = 0; oc < OCH; oc++) acc[oc] += w[(oc * CI + c) * KNN + kn] * s;
        }
    }
    float* outp = out + n * (OCH * HW) + r;
#pragma unroll
    for (int oc = 0; oc < OCH; oc++) outp[oc * HW] = acc[oc];
}

extern "C" void kernel_launch(void* const* d_in, const int* in_sizes, int n_in,
                              void* d_out, int out_size, void* d_ws, size_t ws_size,
                              hipStream_t stream) {
    const float* x = (const float*)d_in[0];
    const float* off = (const float*)d_in[1];
    const float* w = (const float*)d_in[2];
    float* out = (float*)d_out;

    const size_t xT_elems = (size_t)NB * HW * CI;             // 4,194,304 u16
    const size_t wf_elems = (size_t)KNN * 2 * 4 * 64 * 8;     // 36,864 u16
    const size_t need = (xT_elems + wf_elems) * sizeof(u16);  // ~8.46 MB

    if (ws_size >= need) {
        u16* xT = (u16*)d_ws;
        u16* wfr = xT + xT_elems;
        const int wf_blocks = (int)((wf_elems + 255) / 256);  // 144
        prep_kernel<<<NB * 256 + wf_blocks, 256, 0, stream>>>(x, w, xT, wfr);
        dcn_main_kernel<<<1024, 256, 0, stream>>>(xT, off, wfr, out);
    } else {
        dcn_fallback_kernel<<<(NB * HW) / 256, 256, 0, stream>>>(x, off, w, out);
    }
}